// Round 4
// baseline (165.000 us; speedup 1.0000x reference)
//
#include <hip/hip_runtime.h>
#include <hip/hip_bf16.h>
#include <cstddef>

typedef __hip_bfloat16 bf16;

#define CAP   1024   // max tracked edges with dst==0 (expected ~32)
#define MASKW 3328   // LDS bloom words: covers node ids < 106496 (N=100000)

struct Ws {
    int   count;      // #edges with dst==0
    int   done;       // k_gi completion counter (last-block pattern)
    int   pad[14];
    int   degs[CAP];  // per-list-slot in-degree (excl. self loop)
    float agg[128];   // agg row 0 accumulator
    // ---- end of memset region ----
    int   srcs[CAP];  // src of each dst==0 edge
    float gi[768];    // GRU input-gate partials
    float gh[768];    // GRU hidden-gate partials
};

// dtype-adaptive float load (wave-uniform branch)
__device__ __forceinline__ float ldf(const void* p, int isf32, long long i) {
    if (isf32) return ((const float*)p)[i];
    return __bfloat162float(((const bf16*)p)[i]);
}

// per-wave dtype/width detection: ~80 L1-hit loads + 2 ballots
__device__ __forceinline__ void detect(const void* ei, const void* wenc,
                                       int& is64, int& isf32) {
    int l = threadIdx.x & 63;
    // int64 indices < 1e5 -> all high 32-bit words zero; int32 layout -> odd
    // words are random node ids (P(16 zeros) ~ 1e-80).
    int hi = (l < 16) ? ((const int*)ei)[2 * l + 1] : 0;
    unsigned long long any_hi = __ballot(hi != 0);
    // fp32 low-mantissa halves are uniform 16-bit words -> some have
    // bf16-exponent >= 137; bf16 N(0,0.05) data never does.
    unsigned short u = ((const unsigned short*)wenc)[l];
    unsigned short ex = (u >> 7) & 0xFF;
    unsigned long long any_big = __ballot(ex >= 137);
    is64  = (any_hi == 0ull) ? 1 : 0;
    isf32 = (any_big != 0ull) ? 1 : 0;
}

// ---- 1. fused: edge scan (find dst==0) + GRU hh matvec -------------------
__global__ void k_scan1(const void* __restrict__ ei, long long E, int EB,
                        const void* __restrict__ wenc,
                        const void* __restrict__ hidden,
                        const void* __restrict__ Whh,
                        const void* __restrict__ bhh,
                        Ws* w) {
    __shared__ float red[4];
    int is64, isf32;
    detect(ei, wenc, is64, isf32);
    int b = blockIdx.x;
    if (b < EB) {
        long long e0 = ((long long)b * blockDim.x + threadIdx.x) * 2;
        if (e0 >= E) return;
        int d0, d1;
        if (is64) {
            longlong2 dd = ((const longlong2*)ei)[(E + e0) >> 1];
            d0 = (int)dd.x; d1 = (int)dd.y;
        } else {
            int2 dd = ((const int2*)ei)[(E + e0) >> 1];
            d0 = dd.x; d1 = dd.y;
        }
        bool h1ok = (e0 + 1 < E);
        if (d0 == 0) {
            int p = atomicAdd(&w->count, 1);
            if (p < CAP) w->srcs[p] = (int)(is64 ? ((const long long*)ei)[e0]
                                                 : (long long)((const int*)ei)[e0]);
        }
        if (h1ok && d1 == 0) {
            int p = atomicAdd(&w->count, 1);
            if (p < CAP) w->srcs[p] = (int)(is64 ? ((const long long*)ei)[e0 + 1]
                                                 : (long long)((const int*)ei)[e0 + 1]);
        }
    } else {
        // gh[j] = Whh[j,:] . hidden + bhh[j]
        int j = b - EB;
        int t = threadIdx.x;   // 0..255
        float p = ldf(Whh, isf32, (long long)j * 256 + t) * ldf(hidden, isf32, t);
        #pragma unroll
        for (int off = 32; off > 0; off >>= 1) p += __shfl_down(p, off);
        if ((t & 63) == 0) red[t >> 6] = p;
        __syncthreads();
        if (t == 0)
            w->gh[j] = red[0] + red[1] + red[2] + red[3] + ldf(bhh, isf32, j);
    }
}

// ---- 2. in-degree of listed srcs: LDS bloom + exact match on hit ---------
__global__ void k_deg(const void* __restrict__ ei, long long E,
                      const void* __restrict__ wenc, Ws* w) {
    __shared__ unsigned int mask[MASKW];
    __shared__ int ss[CAP];
    int is64, isf32;
    detect(ei, wenc, is64, isf32);
    int cnt = min(w->count, CAP);
    for (int i = threadIdx.x; i < MASKW; i += blockDim.x) mask[i] = 0u;
    __syncthreads();
    for (int i = threadIdx.x; i < cnt; i += blockDim.x) {
        int s = w->srcs[i];
        ss[i] = s;
        if ((unsigned)s < MASKW * 32u)
            atomicOr(&mask[s >> 5], 1u << (s & 31));
    }
    __syncthreads();
    long long e0 = ((long long)blockIdx.x * blockDim.x + threadIdx.x) * 2;
    if (e0 >= E) return;
    int d0, d1;
    if (is64) {
        longlong2 dd = ((const longlong2*)ei)[(E + e0) >> 1];
        d0 = (int)dd.x; d1 = (int)dd.y;
    } else {
        int2 dd = ((const int2*)ei)[(E + e0) >> 1];
        d0 = dd.x; d1 = dd.y;
    }
    bool h1ok = (e0 + 1 < E);
    bool t0 = ((unsigned)d0 < MASKW * 32u) ? ((mask[d0 >> 5] >> (d0 & 31)) & 1u) : true;
    bool t1 = h1ok && (((unsigned)d1 < MASKW * 32u) ? ((mask[d1 >> 5] >> (d1 & 31)) & 1u) : true);
    if (t0) for (int j = 0; j < cnt; j++) if (ss[j] == d0) atomicAdd(&w->degs[j], 1);
    if (t1) for (int j = 0; j < cnt; j++) if (ss[j] == d1) atomicAdd(&w->degs[j], 1);
}

// ---- 3. encoder + GCN matvec for the ~33 relevant nodes ------------------
__global__ void k_gather(const void* __restrict__ nf,
                         const void* __restrict__ Wenc,
                         const void* __restrict__ benc,
                         const void* __restrict__ Wgcn,
                         const void* __restrict__ ei,
                         Ws* w) {
    __shared__ float enc[128];
    __shared__ float nrow[64];
    int is64, isf32;
    detect(ei, Wenc, is64, isf32);
    (void)is64;
    int cnt  = min(w->count, CAP);
    int deg0 = w->count + 1;           // self loop included
    int t = threadIdx.x;               // 0..127
    for (int i = blockIdx.x; i <= cnt; i += gridDim.x) {
        int s; float norm;
        if (i < cnt) {
            s = w->srcs[i];
            norm = rsqrtf((float)(w->degs[i] + 1)) * rsqrtf((float)deg0);
        } else {                        // self loop (0,0)
            s = 0;
            norm = 1.0f / (float)deg0;
        }
        if (t < 64) nrow[t] = ldf(nf, isf32, (long long)s * 64 + t);
        __syncthreads();
        float acc = 0.0f;
        if (isf32) {
            const float4* wr = (const float4*)((const float*)Wenc + (size_t)t * 64);
            #pragma unroll
            for (int k = 0; k < 16; k++) {
                float4 v = wr[k];
                acc += v.x * nrow[4*k] + v.y * nrow[4*k+1]
                     + v.z * nrow[4*k+2] + v.w * nrow[4*k+3];
            }
        } else {
            for (int k = 0; k < 64; k++)
                acc += ldf(Wenc, 0, (long long)t * 64 + k) * nrow[k];
        }
        acc += ldf(benc, isf32, t);
        enc[t] = fmaxf(acc, 0.0f);
        __syncthreads();
        float acc2 = 0.0f;
        if (isf32) {
            const float4* gr = (const float4*)((const float*)Wgcn + (size_t)t * 128);
            #pragma unroll
            for (int k = 0; k < 32; k++) {
                float4 v = gr[k];
                acc2 += v.x * enc[4*k] + v.y * enc[4*k+1]
                      + v.z * enc[4*k+2] + v.w * enc[4*k+3];
            }
        } else {
            for (int k = 0; k < 128; k++)
                acc2 += ldf(Wgcn, 0, (long long)t * 128 + k) * enc[k];
        }
        atomicAdd(&w->agg[t], norm * acc2);
        __syncthreads();               // enc/nrow reused next iteration
    }
}

// ---- 4. GRU gi matvec (768 waves) + last-block gates + output ------------
__global__ void __launch_bounds__(64) k_gi(const void* __restrict__ ei,
                                           const void* __restrict__ wenc,
                                           Ws* __restrict__ w,
                                           const void* __restrict__ bgcn,
                                           const void* __restrict__ hidden,
                                           const void* __restrict__ Wih,
                                           const void* __restrict__ bih,
                                           void* __restrict__ out) {
    __shared__ int lastFlag;
    int is64, isf32;
    detect(ei, wenc, is64, isf32);
    (void)is64;
    int j = blockIdx.x;                // 0..767
    int lane = threadIdx.x;            // 0..63
    float a = 0.0f;
    #pragma unroll
    for (int p = 0; p < 2; p++) {
        int k = lane + 64 * p;
        float g0 = fmaxf(w->agg[k] + ldf(bgcn, isf32, k), 0.0f);
        a += ldf(Wih, isf32, (long long)j * 128 + k) * g0;
    }
    #pragma unroll
    for (int off = 32; off > 0; off >>= 1) a += __shfl_down(a, off);
    if (lane == 0) w->gi[j] = a + ldf(bih, isf32, j);

    // last finishing block computes the gates (release/acquire via fences)
    __threadfence();
    if (lane == 0) {
        int old = atomicAdd(&w->done, 1);
        lastFlag = (old == (int)gridDim.x - 1) ? 1 : 0;
    }
    __syncthreads();
    if (!lastFlag) return;
    __threadfence();
    volatile float* vgi = w->gi;
    volatile float* vgh = w->gh;
    #pragma unroll
    for (int q = 0; q < 4; q++) {
        int t = lane + 64 * q;         // 0..255
        float r = 1.0f / (1.0f + expf(-(vgi[t]       + vgh[t])));
        float z = 1.0f / (1.0f + expf(-(vgi[256 + t] + vgh[256 + t])));
        float n = tanhf(vgi[512 + t] + r * vgh[512 + t]);
        float h = ldf(hidden, isf32, t);
        float val = (1.0f - z) * n + z * h;
        if (isf32) ((float*)out)[t] = val;
        else       ((bf16*)out)[t] = __float2bfloat16(val);
    }
}

extern "C" void kernel_launch(void* const* d_in, const int* in_sizes, int n_in,
                              void* d_out, int out_size, void* d_ws, size_t ws_size,
                              hipStream_t stream) {
    const void* nf   = d_in[0];
    // d_in[1] edge_attr: unused by the reference
    const void* hid  = d_in[2];
    const void* Wenc = d_in[3];
    const void* benc = d_in[4];
    const void* Wgcn = d_in[5];
    const void* bgcn = d_in[6];
    const void* Wih  = d_in[7];
    const void* Whh  = d_in[8];
    const void* bih  = d_in[9];
    const void* bhh  = d_in[10];
    const void* ei   = d_in[11];
    long long E = in_sizes[11] / 2;

    Ws* w = (Ws*)d_ws;
    hipMemsetAsync(w, 0, offsetof(Ws, srcs), stream);   // count/done/degs/agg = 0

    int EB = (int)(((E + 1) / 2 + 255) / 256);          // 2 edges per thread
    k_scan1<<<EB + 768, 256, 0, stream>>>(ei, E, EB, Wenc, hid, Whh, bhh, w);
    k_deg<<<EB, 256, 0, stream>>>(ei, E, Wenc, w);
    k_gather<<<64, 128, 0, stream>>>(nf, Wenc, benc, Wgcn, ei, w);
    k_gi<<<768, 64, 0, stream>>>(ei, Wenc, w, bgcn, hid, Wih, bih, d_out);
}